// Round 4
// baseline (1303.466 us; speedup 1.0000x reference)
//
#include <hip/hip_runtime.h>

// Problem constants
#define BB    512
#define TT    300
#define DD    128
#define HH    256
#define GG    1024      // 4*H
#define DNS   256
#define NC    14
#define KDIM  76800     // T*H

typedef _Float16 f16;
typedef _Float16 f16x8 __attribute__((ext_vector_type(8)));
typedef float    f32x4 __attribute__((ext_vector_type(4)));

__device__ __forceinline__ float sigf(float x){ return 1.0f / (1.0f + __expf(-x)); }
__device__ __forceinline__ float tanhfast(float x){ return 2.0f / (1.0f + __expf(-2.0f*x)) - 1.0f; }

// ---------------- K1: embedding gather, fp32 -> fp16 x[B][T][D] ----------------
__global__ void k_gather(const int* __restrict__ idx, const float* __restrict__ emb,
                         f16* __restrict__ xbuf)
{
    int gid = blockIdx.x * 256 + threadIdx.x;       // one 4-dim chunk
    if (gid >= BB*TT*DD/4) return;
    int bt = gid >> 5;                              // 32 chunks per 128-dim row
    int c4 = gid & 31;
    int v  = idx[bt];
    const float4 e = *(const float4*)(emb + (size_t)v*DD + c4*4);
    union { f16 h[4]; uint2 u; } o;
    o.h[0]=(f16)e.x; o.h[1]=(f16)e.y; o.h[2]=(f16)e.z; o.h[3]=(f16)e.w;
    *(uint2*)(xbuf + (size_t)bt*DD + c4*4) = o.u;
}

// ---------------- K1b: W3 fp32 -> fp16 ----------------
__global__ void k_w3cvt(const float* __restrict__ W3, f16* __restrict__ W3h)
{
    int gid = blockIdx.x * 256 + threadIdx.x;       // one float4
    if (gid >= DNS*KDIM/4) return;
    const float4 e = *(const float4*)(W3 + (size_t)gid*4);
    union { f16 h[4]; uint2 u; } o;
    o.h[0]=(f16)e.x; o.h[1]=(f16)e.y; o.h[2]=(f16)e.z; o.h[3]=(f16)e.w;
    *(uint2*)(W3h + (size_t)gid*4) = o.u;
}

// ---------------- K2: persistent LSTM recurrence ----------------
// Grid: 256 blocks = 16 h-slices (hsI) x 16 batch-slices (bsI); 512 threads (8 waves).
// W slice resident in registers. Cross-block h exchange via agent-scope RELAXED
// 8B atomics (device-coherent at the MALL) -> no cache fences.
// Sync (round 4): per-block FLAG ARRAY instead of a single shared RMW counter.
// 16 atomic fetch_adds on one line serialized ~250cyc each at the coherence
// point (~3500 cyc/step, the round-3 gap). Now: tid0 stores flag[me]=t+1 after
// the vmcnt-draining __syncthreads; tids 0..15 busy-poll the 16 peer flags on
// independent 64B-spaced lines (read-shared, no serialization).
__global__ __launch_bounds__(512) void k_lstm(
    const f16* __restrict__ xbuf, f16* __restrict__ hs,
    const float* __restrict__ Wih, const float* __restrict__ Whh,
    const float* __restrict__ bih, const float* __restrict__ bhh,
    unsigned int* cnt)
{
    __shared__ f16   Ast[32*392];    // 32 rows x (256 h | 128 x | 8 pad) halves
    __shared__ float gbuf[32*68];    // gates [row][q] (q=4*d+ty), pad 68
    __shared__ float biasS[64];

    const int tid  = threadIdx.x;
    const int bsI  = blockIdx.x & 15, hsI = blockIdx.x >> 4;
    const int r0   = bsI*32, j0 = hsI*16;
    const int wv   = tid >> 6, lane = tid & 63;
    const int q16  = lane & 15, quad = lane >> 4;
    const int mt   = wv >> 2, nt = wv & 3;          // wave -> (m-subtile, n-subtile)

    // ---- load resident W fragments: lane holds W[q = nt*16+q16][k-chunks] ----
    f16x8 bf[12];
    {
        const int ql   = nt*16 + q16;
        const int drow = ql >> 2, ty = ql & 3;      // q = 4*d + ty
        const int Grow = ty*HH + j0 + drow;         // global gate row
        const float* wh = Whh + (size_t)Grow*HH;
        #pragma unroll
        for (int kk = 0; kk < 8; ++kk) {
            const float* p = wh + kk*32 + quad*8;
            float4 f0 = *(const float4*)p, f1 = *(const float4*)(p+4);
            f16x8 b;
            b[0]=(f16)f0.x; b[1]=(f16)f0.y; b[2]=(f16)f0.z; b[3]=(f16)f0.w;
            b[4]=(f16)f1.x; b[5]=(f16)f1.y; b[6]=(f16)f1.z; b[7]=(f16)f1.w;
            bf[kk] = b;
        }
        const float* wi = Wih + (size_t)Grow*DD;
        #pragma unroll
        for (int kk = 0; kk < 4; ++kk) {
            const float* p = wi + kk*32 + quad*8;
            float4 f0 = *(const float4*)p, f1 = *(const float4*)(p+4);
            f16x8 b;
            b[0]=(f16)f0.x; b[1]=(f16)f0.y; b[2]=(f16)f0.z; b[3]=(f16)f0.w;
            b[4]=(f16)f1.x; b[5]=(f16)f1.y; b[6]=(f16)f1.z; b[7]=(f16)f1.w;
            bf[8+kk] = b;
        }
    }
    if (tid < 64) {
        const int drow = tid >> 2, ty = tid & 3;
        const int Grow = ty*HH + j0 + drow;
        biasS[tid] = bih[Grow] + bhh[Grow];
    }

    float c = 0.0f;                                  // cell state, resident
    const int pr = tid >> 4;                         // local batch row 0..31
    const int pd = tid & 15;                         // local h-dim 0..15
    unsigned int* grpFlags = cnt + bsI*16*16;        // 16 flags x 16 uints (64B) apart

    for (int t = 0; t < TT; ++t) {
        // ---- stage h_{t-1}: 32 rows x 64 8B-chunks (agent-scope atomic loads) ----
        if (t > 0) {
            #pragma unroll
            for (int rep = 0; rep < 4; ++rep) {
                int id  = tid + rep*512;             // 0..2047
                int row = id >> 6, ch = id & 63;     // 8B chunk (4 halves)
                unsigned long long* hp = (unsigned long long*)
                    (hs + ((size_t)(r0+row)*TT + (t-1))*HH) + ch;
                unsigned long long v = __hip_atomic_load(hp, __ATOMIC_RELAXED,
                                                         __HIP_MEMORY_SCOPE_AGENT);
                *(unsigned long long*)(Ast + (size_t)row*392 + ch*4) = v;
            }
        } else {
            #pragma unroll
            for (int rep = 0; rep < 4; ++rep) {
                int id  = tid + rep*512;
                int row = id >> 6, ch = id & 63;
                *(unsigned long long*)(Ast + (size_t)row*392 + ch*4) = 0ull;
            }
        }
        // ---- stage x_t: 32 rows x 16 16B-chunks (normal cached loads) ----
        {
            int row = tid >> 4, ch = tid & 15;
            uint4 val = *(const uint4*)(xbuf + ((size_t)(r0+row)*TT + t)*DD + ch*8);
            *(uint4*)(Ast + (size_t)row*392 + 256 + ch*8) = val;
        }
        __syncthreads();

        // ---- gates[r][q] = sum_k A[r,k] * W[q,k] ----
        f32x4 acc = {0.f, 0.f, 0.f, 0.f};
        const f16* arow = Ast + (mt*16 + q16)*392 + quad*8;
        #pragma unroll
        for (int kk = 0; kk < 12; ++kk) {
            f16x8 a = *(const f16x8*)(arow + kk*32);
            acc = __builtin_amdgcn_mfma_f32_16x16x32_f16(a, bf[kk], acc, 0, 0, 0);
        }
        // D layout: col=lane&15 -> q, row=quad*4+reg -> m. Store to gbuf[m][q].
        #pragma unroll
        for (int r = 0; r < 4; ++r)
            gbuf[(mt*16 + quad*4 + r)*68 + nt*16 + q16] = acc[r];
        __syncthreads();

        // ---- elementwise LSTM cell for this thread's (row, dim) ----
        float h;
        {
            const float4 g = *(const float4*)(gbuf + pr*68 + pd*4);
            float gi = g.x + biasS[pd*4+0];
            float gf = g.y + biasS[pd*4+1];
            float gg = g.z + biasS[pd*4+2];
            float go = g.w + biasS[pd*4+3];
            float iv = sigf(gi), fv = sigf(gf), gv = tanhfast(gg), ov = sigf(go);
            c = fv*c + iv*gv;
            h = ov * tanhfast(c);
        }
        // pack 4 consecutive dims (lanes pd..pd+3) into one 8B store
        {
            union { unsigned short us; f16 hf; } cv; cv.hf = (f16)h;
            unsigned int hb = cv.us;
            unsigned int nb = (unsigned int)__shfl_xor((int)hb, 1, 64);
            unsigned int p32 = hb | (nb << 16);               // valid on even lanes
            unsigned int q32 = (unsigned int)__shfl_xor((int)p32, 2, 64);
            if ((lane & 3) == 0) {
                unsigned long long v = (unsigned long long)p32
                                     | ((unsigned long long)q32 << 32);
                unsigned long long* dp = (unsigned long long*)
                    (hs + ((size_t)(r0+pr)*TT + t)*HH + j0 + pd);
                __hip_atomic_store(dp, v, __ATOMIC_RELAXED,
                                   __HIP_MEMORY_SCOPE_AGENT);
            }
        }

        // ---- group sync: flag-array, no RMW contention ----
        __syncthreads();            // drains vmcnt(0): h stores at coherence point
        if (tid == 0)
            __hip_atomic_store(grpFlags + hsI*16, (unsigned)(t+1),
                               __ATOMIC_RELAXED, __HIP_MEMORY_SCOPE_AGENT);
        if (tid < 16) {
            unsigned int* f = grpFlags + tid*16;
            while (__hip_atomic_load(f, __ATOMIC_RELAXED,
                                     __HIP_MEMORY_SCOPE_AGENT) < (unsigned)(t+1)) { }
        }
        __syncthreads();
        // no acquire fence: all cross-block data reads are agent-scope atomics
    }
}

// ---------------- K3: dense GEMM, split-K -> partials ----------------
__global__ __launch_bounds__(256) void k_dense(
    const f16* __restrict__ hs, const f16* __restrict__ W3h, float* __restrict__ part)
{
    __shared__ f16 Ap[128*40];
    __shared__ f16 Bp[128*40];
    const int tid = threadIdx.x;
    const int kb = blockIdx.x & 31, tn = (blockIdx.x >> 5) & 1, tm = blockIdx.x >> 6;
    const int m0 = tm*128, n0 = tn*128;
    const long k0 = (long)kb * 2400;
    const int wv = tid >> 6, lane = tid & 63, q16 = lane & 15, quad = lane >> 4;

    f32x4 acc[2][8];
    #pragma unroll
    for (int a = 0; a < 2; ++a)
        #pragma unroll
        for (int b = 0; b < 8; ++b) acc[a][b] = (f32x4){0.f,0.f,0.f,0.f};

    for (int ks = 0; ks < 75; ++ks) {
        const long kbase = k0 + ks*32;
        #pragma unroll
        for (int rep = 0; rep < 4; ++rep) {
            int cid = tid + rep*256;                 // 1024 chunks: 512 A + 512 B
            int selB = cid >> 9;
            int rrow = (cid & 511) >> 2;
            int c4   = cid & 3;
            const f16* src = selB
                ? (W3h + (size_t)(n0+rrow)*KDIM + kbase + c4*8)
                : (hs  + (size_t)(m0+rrow)*KDIM + kbase + c4*8);
            f16* dst = (selB ? Bp : Ap) + rrow*40 + c4*8;
            *(uint4*)dst = *(const uint4*)src;
        }
        __syncthreads();

        f16x8 a0 = *(const f16x8*)(Ap + ((wv*2+0)*16 + q16)*40 + quad*8);
        f16x8 a1 = *(const f16x8*)(Ap + ((wv*2+1)*16 + q16)*40 + quad*8);
        #pragma unroll
        for (int ns = 0; ns < 8; ++ns) {
            f16x8 b = *(const f16x8*)(Bp + (ns*16 + q16)*40 + quad*8);
            acc[0][ns] = __builtin_amdgcn_mfma_f32_16x16x32_f16(a0, b, acc[0][ns], 0,0,0);
            acc[1][ns] = __builtin_amdgcn_mfma_f32_16x16x32_f16(a1, b, acc[1][ns], 0,0,0);
        }
        __syncthreads();
    }
    #pragma unroll
    for (int ms = 0; ms < 2; ++ms)
        #pragma unroll
        for (int ns = 0; ns < 8; ++ns)
            #pragma unroll
            for (int r = 0; r < 4; ++r) {
                int m = m0 + (wv*2+ms)*16 + quad*4 + r;
                int n = n0 + ns*16 + q16;
                part[(size_t)kb*BB*DNS + (size_t)m*DNS + n] = acc[ms][ns][r];
            }
}

// ---------------- K4: reduce split-K partials + bias + relu ----------------
__global__ void k_reduce(const float* __restrict__ part, const float* __restrict__ b3,
                         float* __restrict__ dens)
{
    int g = blockIdx.x * 256 + threadIdx.x;
    if (g >= BB*DNS) return;
    int n = g & 255;
    float s = b3[n];
    #pragma unroll
    for (int kb = 0; kb < 32; ++kb) s += part[(size_t)kb*BB*DNS + g];
    dens[g] = fmaxf(s, 0.0f);
}

// ---------------- K5: final 256->14 + softmax ----------------
__global__ __launch_bounds__(64) void k_final(
    const float* __restrict__ dens, const float* __restrict__ W4,
    const float* __restrict__ b4, float* __restrict__ out)
{
    const int b = blockIdx.x, lane = threadIdx.x;
    const float4 dv = *(const float4*)(dens + (size_t)b*DNS + lane*4);
    float lg[NC];
    #pragma unroll
    for (int cc = 0; cc < NC; ++cc) {
        const float4 w = *(const float4*)(W4 + (size_t)cc*DNS + lane*4);
        float v = dv.x*w.x + dv.y*w.y + dv.z*w.z + dv.w*w.w;
        #pragma unroll
        for (int off = 32; off; off >>= 1) v += __shfl_xor(v, off, 64);
        lg[cc] = v + b4[cc];
    }
    if (lane == 0) {
        float m = lg[0];
        #pragma unroll
        for (int cc = 1; cc < NC; ++cc) m = fmaxf(m, lg[cc]);
        float e[NC], s = 0.f;
        #pragma unroll
        for (int cc = 0; cc < NC; ++cc) { e[cc] = __expf(lg[cc]-m); s += e[cc]; }
        const float inv = 1.0f/s;
        #pragma unroll
        for (int cc = 0; cc < NC; ++cc) out[(size_t)b*NC + cc] = e[cc]*inv;
    }
}

// ---------------- launch ----------------
extern "C" void kernel_launch(void* const* d_in, const int* in_sizes, int n_in,
                              void* d_out, int out_size, void* d_ws, size_t ws_size,
                              hipStream_t stream)
{
    const int*   idx = (const int*)  d_in[0];
    // d_in[1] = traj_lens: unused by the reference
    const float* emb = (const float*)d_in[2];
    const float* Wih = (const float*)d_in[3];
    const float* Whh = (const float*)d_in[4];
    const float* bih = (const float*)d_in[5];
    const float* bhh = (const float*)d_in[6];
    const float* W3  = (const float*)d_in[7];
    const float* b3  = (const float*)d_in[8];
    const float* W4  = (const float*)d_in[9];
    const float* b4  = (const float*)d_in[10];
    float* out = (float*)d_out;

    char* ws = (char*)d_ws;
    f16*   xbuf = (f16*)  (ws);                           // 39,321,600 B
    f16*   hs   = (f16*)  (ws + 39321600);                // 78,643,200 B
    f16*   W3h  = (f16*)  (ws + 117964800);               // 39,321,600 B
    float* part = (float*)(ws + 157286400);               // 16,777,216 B
    float* dens = (float*)(ws + 174063616);               //    524,288 B
    unsigned int* cnt = (unsigned int*)(ws + 174587904);  //     16,384 B flags

    hipMemsetAsync(cnt, 0, 16384, stream);
    k_gather<<<19200, 256, 0, stream>>>(idx, emb, xbuf);
    k_w3cvt <<<19200, 256, 0, stream>>>(W3, W3h);
    k_lstm  <<<256, 512, 0, stream>>>(xbuf, hs, Wih, Whh, bih, bhh, cnt);
    k_dense <<<256, 256, 0, stream>>>(hs, W3h, part);
    k_reduce<<<512, 256, 0, stream>>>(part, b3, dens);
    k_final <<<BB, 64, 0, stream>>>(dens, W4, b4, out);
}

// Round 5
// 1089.002 us; speedup vs baseline: 1.1969x; 1.1969x over previous
//
#include <hip/hip_runtime.h>

// Problem constants
#define BB    512
#define TT    300
#define DD    128
#define HH    256
#define GG    1024      // 4*H
#define DNS   256
#define NC    14
#define KDIM  76800     // T*H

typedef _Float16 f16;
typedef _Float16 f16x8 __attribute__((ext_vector_type(8)));
typedef float    f32x4 __attribute__((ext_vector_type(4)));

__device__ __forceinline__ float sigf(float x){ return 1.0f / (1.0f + __expf(-x)); }
__device__ __forceinline__ float tanhfast(float x){ return 2.0f / (1.0f + __expf(-2.0f*x)) - 1.0f; }

// ---------------- K1: embedding gather, fp32 -> fp16 x[B][T][D] ----------------
__global__ void k_gather(const int* __restrict__ idx, const float* __restrict__ emb,
                         f16* __restrict__ xbuf)
{
    int gid = blockIdx.x * 256 + threadIdx.x;       // one 4-dim chunk
    if (gid >= BB*TT*DD/4) return;
    int bt = gid >> 5;                              // 32 chunks per 128-dim row
    int c4 = gid & 31;
    int v  = idx[bt];
    const float4 e = *(const float4*)(emb + (size_t)v*DD + c4*4);
    union { f16 h[4]; uint2 u; } o;
    o.h[0]=(f16)e.x; o.h[1]=(f16)e.y; o.h[2]=(f16)e.z; o.h[3]=(f16)e.w;
    *(uint2*)(xbuf + (size_t)bt*DD + c4*4) = o.u;
}

// ---------------- K1b: W3 fp32 -> fp16 ----------------
__global__ void k_w3cvt(const float* __restrict__ W3, f16* __restrict__ W3h)
{
    int gid = blockIdx.x * 256 + threadIdx.x;       // one float4
    if (gid >= DNS*KDIM/4) return;
    const float4 e = *(const float4*)(W3 + (size_t)gid*4);
    union { f16 h[4]; uint2 u; } o;
    o.h[0]=(f16)e.x; o.h[1]=(f16)e.y; o.h[2]=(f16)e.z; o.h[3]=(f16)e.w;
    *(uint2*)(W3h + (size_t)gid*4) = o.u;
}

// ---------------- K2: persistent LSTM recurrence ----------------
// Grid: 256 blocks = 16 h-slices (hsI) x 16 batch-slices (bsI); 512 threads (8 waves).
// W slice resident in registers. Cross-block h exchange via agent-scope RELAXED
// 8B atomics (device-coherent at the MALL) -> no cache fences.
// Round-5 sync: per-producer DATAFLOW, not a barrier. Each thread's 4 staging
// loads all read chunk ch==lane -> exactly ONE producer (lane>>2). Producer
// stores flag[hsI]=t+1 (plain agent store, after vmcnt-draining syncthreads);
// each consumer lane waits only on its own producer's flag, then loads.
// A block's OWN 16 dims never round-trip the MALL: elementwise writes them
// straight into Ast (LDS), so nobody waits on its own flag (stored last).
// Removes 2 of 4 per-step __syncthreads + tolerates producer skew.
__global__ __launch_bounds__(512) void k_lstm(
    const f16* __restrict__ xbuf, f16* __restrict__ hs,
    const float* __restrict__ Wih, const float* __restrict__ Whh,
    const float* __restrict__ bih, const float* __restrict__ bhh,
    unsigned int* cnt)
{
    __shared__ f16   Ast[32*392];    // 32 rows x (256 h | 128 x | 8 pad) halves
    __shared__ float gbuf[32*68];    // gates [row][q] (q=4*d+ty), pad 68
    __shared__ float biasS[64];

    const int tid  = threadIdx.x;
    const int bsI  = blockIdx.x & 15, hsI = blockIdx.x >> 4;
    const int r0   = bsI*32, j0 = hsI*16;
    const int wv   = tid >> 6, lane = tid & 63;
    const int q16  = lane & 15, quad = lane >> 4;
    const int mt   = wv >> 2, nt = wv & 3;          // wave -> (m-subtile, n-subtile)

    // ---- load resident W fragments: lane holds W[q = nt*16+q16][k-chunks] ----
    f16x8 bf[12];
    {
        const int ql   = nt*16 + q16;
        const int drow = ql >> 2, ty = ql & 3;      // q = 4*d + ty
        const int Grow = ty*HH + j0 + drow;         // global gate row
        const float* wh = Whh + (size_t)Grow*HH;
        #pragma unroll
        for (int kk = 0; kk < 8; ++kk) {
            const float* p = wh + kk*32 + quad*8;
            float4 f0 = *(const float4*)p, f1 = *(const float4*)(p+4);
            f16x8 b;
            b[0]=(f16)f0.x; b[1]=(f16)f0.y; b[2]=(f16)f0.z; b[3]=(f16)f0.w;
            b[4]=(f16)f1.x; b[5]=(f16)f1.y; b[6]=(f16)f1.z; b[7]=(f16)f1.w;
            bf[kk] = b;
        }
        const float* wi = Wih + (size_t)Grow*DD;
        #pragma unroll
        for (int kk = 0; kk < 4; ++kk) {
            const float* p = wi + kk*32 + quad*8;
            float4 f0 = *(const float4*)p, f1 = *(const float4*)(p+4);
            f16x8 b;
            b[0]=(f16)f0.x; b[1]=(f16)f0.y; b[2]=(f16)f0.z; b[3]=(f16)f0.w;
            b[4]=(f16)f1.x; b[5]=(f16)f1.y; b[6]=(f16)f1.z; b[7]=(f16)f1.w;
            bf[8+kk] = b;
        }
    }
    if (tid < 64) {
        const int drow = tid >> 2, ty = tid & 3;
        const int Grow = ty*HH + j0 + drow;
        biasS[tid] = bih[Grow] + bhh[Grow];
    }

    float c = 0.0f;                                  // cell state, resident
    const int pr = tid >> 4;                         // local batch row 0..31
    const int pd = tid & 15;                         // local h-dim 0..15
    unsigned int* grpFlags = cnt + bsI*256;          // 16 producer flags, 64B apart
    unsigned int* myFlag   = grpFlags + hsI*16;
    unsigned int* depFlag  = grpFlags + (lane>>2)*16;   // this lane's producer
    const bool ownChunk    = ((lane>>2) == hsI);        // data comes from LDS

    for (int t = 0; t < TT; ++t) {
        // ---- stage x_t: 32 rows x 16 16B-chunks (cached loads; issued pre-wait) ----
        {
            int row = tid >> 4, ch = tid & 15;
            uint4 val = *(const uint4*)(xbuf + ((size_t)(r0+row)*TT + t)*DD + ch*8);
            *(uint4*)(Ast + (size_t)row*392 + 256 + ch*8) = val;
        }
        // ---- stage h_{t-1}: chunk `lane` of rows wv+8*rep; dataflow wait ----
        if (t > 0) {
            if (!ownChunk) {
                while (__hip_atomic_load(depFlag, __ATOMIC_RELAXED,
                                         __HIP_MEMORY_SCOPE_AGENT) < (unsigned)t)
                    __builtin_amdgcn_s_sleep(0);
                #pragma unroll
                for (int rep = 0; rep < 4; ++rep) {
                    int row = wv + rep*8;
                    unsigned long long* hp = (unsigned long long*)
                        (hs + ((size_t)(r0+row)*TT + (t-1))*HH) + lane;
                    unsigned long long v = __hip_atomic_load(hp, __ATOMIC_RELAXED,
                                                             __HIP_MEMORY_SCOPE_AGENT);
                    *(unsigned long long*)(Ast + (size_t)row*392 + lane*4) = v;
                }
            }
            // own chunks already in Ast (written by elementwise at t-1)
        } else {
            #pragma unroll
            for (int rep = 0; rep < 4; ++rep) {
                int row = wv + rep*8;
                *(unsigned long long*)(Ast + (size_t)row*392 + lane*4) = 0ull;
            }
        }
        __syncthreads();   // syncA: Ast complete

        // ---- gates[r][q] = sum_k A[r,k] * W[q,k] ----
        f32x4 acc = {0.f, 0.f, 0.f, 0.f};
        const f16* arow = Ast + (mt*16 + q16)*392 + quad*8;
        #pragma unroll
        for (int kk = 0; kk < 12; ++kk) {
            f16x8 a = *(const f16x8*)(arow + kk*32);
            acc = __builtin_amdgcn_mfma_f32_16x16x32_f16(a, bf[kk], acc, 0, 0, 0);
        }
        // D layout: col=lane&15 -> q, row=quad*4+reg -> m. Store to gbuf[m][q].
        #pragma unroll
        for (int r = 0; r < 4; ++r)
            gbuf[(mt*16 + quad*4 + r)*68 + nt*16 + q16] = acc[r];
        __syncthreads();   // syncB: gates ready (also: all Ast reads done)

        // ---- elementwise LSTM cell for this thread's (row, dim) ----
        float h;
        {
            const float4 g = *(const float4*)(gbuf + pr*68 + pd*4);
            float gi = g.x + biasS[pd*4+0];
            float gf = g.y + biasS[pd*4+1];
            float gg = g.z + biasS[pd*4+2];
            float go = g.w + biasS[pd*4+3];
            float iv = sigf(gi), fv = sigf(gf), gv = tanhfast(gg), ov = sigf(go);
            c = fv*c + iv*gv;
            h = ov * tanhfast(c);
        }
        // own-slice h -> directly into Ast for step t+1 (no MALL round-trip)
        Ast[pr*392 + j0 + pd] = (f16)h;
        // pack 4 consecutive dims (lanes pd..pd+3) into one 8B agent-scope store
        {
            union { unsigned short us; f16 hf; } cv; cv.hf = (f16)h;
            unsigned int hb = cv.us;
            unsigned int nb = (unsigned int)__shfl_xor((int)hb, 1, 64);
            unsigned int p32 = hb | (nb << 16);               // valid on even lanes
            unsigned int q32 = (unsigned int)__shfl_xor((int)p32, 2, 64);
            if ((lane & 3) == 0) {
                unsigned long long v = (unsigned long long)p32
                                     | ((unsigned long long)q32 << 32);
                unsigned long long* dp = (unsigned long long*)
                    (hs + ((size_t)(r0+pr)*TT + t)*HH + j0 + pd);
                __hip_atomic_store(dp, v, __ATOMIC_RELAXED,
                                   __HIP_MEMORY_SCOPE_AGENT);
            }
        }

        // ---- signal: drain h stores, then publish this producer's flag ----
        __syncthreads();   // syncC: drains vmcnt(0) -> h stores at coherence point
        if (tid == 0)
            __hip_atomic_store(myFlag, (unsigned)(t+1),
                               __ATOMIC_RELAXED, __HIP_MEMORY_SCOPE_AGENT);
        // no 4th barrier: next iteration's staging only writes regions whose
        // readers (MFMA of step t) finished before syncB, and syncC has passed.
    }
}

// ---------------- K3: dense GEMM, split-K -> partials ----------------
__global__ __launch_bounds__(256) void k_dense(
    const f16* __restrict__ hs, const f16* __restrict__ W3h, float* __restrict__ part)
{
    __shared__ f16 Ap[128*40];
    __shared__ f16 Bp[128*40];
    const int tid = threadIdx.x;
    const int kb = blockIdx.x & 31, tn = (blockIdx.x >> 5) & 1, tm = blockIdx.x >> 6;
    const int m0 = tm*128, n0 = tn*128;
    const long k0 = (long)kb * 2400;
    const int wv = tid >> 6, lane = tid & 63, q16 = lane & 15, quad = lane >> 4;

    f32x4 acc[2][8];
    #pragma unroll
    for (int a = 0; a < 2; ++a)
        #pragma unroll
        for (int b = 0; b < 8; ++b) acc[a][b] = (f32x4){0.f,0.f,0.f,0.f};

    for (int ks = 0; ks < 75; ++ks) {
        const long kbase = k0 + ks*32;
        #pragma unroll
        for (int rep = 0; rep < 4; ++rep) {
            int cid = tid + rep*256;                 // 1024 chunks: 512 A + 512 B
            int selB = cid >> 9;
            int rrow = (cid & 511) >> 2;
            int c4   = cid & 3;
            const f16* src = selB
                ? (W3h + (size_t)(n0+rrow)*KDIM + kbase + c4*8)
                : (hs  + (size_t)(m0+rrow)*KDIM + kbase + c4*8);
            f16* dst = (selB ? Bp : Ap) + rrow*40 + c4*8;
            *(uint4*)dst = *(const uint4*)src;
        }
        __syncthreads();

        f16x8 a0 = *(const f16x8*)(Ap + ((wv*2+0)*16 + q16)*40 + quad*8);
        f16x8 a1 = *(const f16x8*)(Ap + ((wv*2+1)*16 + q16)*40 + quad*8);
        #pragma unroll
        for (int ns = 0; ns < 8; ++ns) {
            f16x8 b = *(const f16x8*)(Bp + (ns*16 + q16)*40 + quad*8);
            acc[0][ns] = __builtin_amdgcn_mfma_f32_16x16x32_f16(a0, b, acc[0][ns], 0,0,0);
            acc[1][ns] = __builtin_amdgcn_mfma_f32_16x16x32_f16(a1, b, acc[1][ns], 0,0,0);
        }
        __syncthreads();
    }
    #pragma unroll
    for (int ms = 0; ms < 2; ++ms)
        #pragma unroll
        for (int ns = 0; ns < 8; ++ns)
            #pragma unroll
            for (int r = 0; r < 4; ++r) {
                int m = m0 + (wv*2+ms)*16 + quad*4 + r;
                int n = n0 + ns*16 + q16;
                part[(size_t)kb*BB*DNS + (size_t)m*DNS + n] = acc[ms][ns][r];
            }
}

// ---------------- K4: reduce split-K partials + bias + relu ----------------
__global__ void k_reduce(const float* __restrict__ part, const float* __restrict__ b3,
                         float* __restrict__ dens)
{
    int g = blockIdx.x * 256 + threadIdx.x;
    if (g >= BB*DNS) return;
    int n = g & 255;
    float s = b3[n];
    #pragma unroll
    for (int kb = 0; kb < 32; ++kb) s += part[(size_t)kb*BB*DNS + g];
    dens[g] = fmaxf(s, 0.0f);
}

// ---------------- K5: final 256->14 + softmax ----------------
__global__ __launch_bounds__(64) void k_final(
    const float* __restrict__ dens, const float* __restrict__ W4,
    const float* __restrict__ b4, float* __restrict__ out)
{
    const int b = blockIdx.x, lane = threadIdx.x;
    const float4 dv = *(const float4*)(dens + (size_t)b*DNS + lane*4);
    float lg[NC];
    #pragma unroll
    for (int cc = 0; cc < NC; ++cc) {
        const float4 w = *(const float4*)(W4 + (size_t)cc*DNS + lane*4);
        float v = dv.x*w.x + dv.y*w.y + dv.z*w.z + dv.w*w.w;
        #pragma unroll
        for (int off = 32; off; off >>= 1) v += __shfl_xor(v, off, 64);
        lg[cc] = v + b4[cc];
    }
    if (lane == 0) {
        float m = lg[0];
        #pragma unroll
        for (int cc = 1; cc < NC; ++cc) m = fmaxf(m, lg[cc]);
        float e[NC], s = 0.f;
        #pragma unroll
        for (int cc = 0; cc < NC; ++cc) { e[cc] = __expf(lg[cc]-m); s += e[cc]; }
        const float inv = 1.0f/s;
        #pragma unroll
        for (int cc = 0; cc < NC; ++cc) out[(size_t)b*NC + cc] = e[cc]*inv;
    }
}

// ---------------- launch ----------------
extern "C" void kernel_launch(void* const* d_in, const int* in_sizes, int n_in,
                              void* d_out, int out_size, void* d_ws, size_t ws_size,
                              hipStream_t stream)
{
    const int*   idx = (const int*)  d_in[0];
    // d_in[1] = traj_lens: unused by the reference
    const float* emb = (const float*)d_in[2];
    const float* Wih = (const float*)d_in[3];
    const float* Whh = (const float*)d_in[4];
    const float* bih = (const float*)d_in[5];
    const float* bhh = (const float*)d_in[6];
    const float* W3  = (const float*)d_in[7];
    const float* b3  = (const float*)d_in[8];
    const float* W4  = (const float*)d_in[9];
    const float* b4  = (const float*)d_in[10];
    float* out = (float*)d_out;

    char* ws = (char*)d_ws;
    f16*   xbuf = (f16*)  (ws);                           // 39,321,600 B
    f16*   hs   = (f16*)  (ws + 39321600);                // 78,643,200 B
    f16*   W3h  = (f16*)  (ws + 117964800);               // 39,321,600 B
    float* part = (float*)(ws + 157286400);               // 16,777,216 B
    float* dens = (float*)(ws + 174063616);               //    524,288 B
    unsigned int* cnt = (unsigned int*)(ws + 174587904);  //     16,384 B flags

    hipMemsetAsync(cnt, 0, 16384, stream);
    k_gather<<<19200, 256, 0, stream>>>(idx, emb, xbuf);
    k_w3cvt <<<19200, 256, 0, stream>>>(W3, W3h);
    k_lstm  <<<256, 512, 0, stream>>>(xbuf, hs, Wih, Whh, bih, bhh, cnt);
    k_dense <<<256, 256, 0, stream>>>(hs, W3h, part);
    k_reduce<<<512, 256, 0, stream>>>(part, b3, dens);
    k_final <<<BB, 64, 0, stream>>>(dens, W4, b4, out);
}